// Round 8
// baseline (208.575 us; speedup 1.0000x reference)
//
#include <hip/hip_runtime.h>
#include <math.h>

#define BS        4
#define NQ        300
#define NK        17
#define LEN_Q     5100          // NQ*NK
#define N_HEADS   8
#define N_LEVELS  4
#define N_POINTS  4
#define D_MODEL   256
#define HD        32            // D_MODEL / N_HEADS

// transposed-value level bases (floats), layout vt[l][n][s][c], c contiguous
#define LB0 0
#define LB1 16777216            // + 32*16384*32
#define LB2 20971520            // + 32*4096*32
#define LB3 22020096            // + 32*1024*32
#define VT_TOTAL 22282240       // + 32*256*32
#define PROJ_OFF VT_TOTAL       // proj: (BS*LEN_Q, 384) floats

typedef __attribute__((ext_vector_type(8))) short bf16x8;
typedef __attribute__((ext_vector_type(4))) float f32x4;

// ---------------------------------------------------------------------------
// 32xS -> Sx32 transpose per n (classic LDS tile). block (32,8), grid (S/32, 32)
// ---------------------------------------------------------------------------
__global__ __launch_bounds__(256) void transpose_kernel(
    const float* __restrict__ in, float* __restrict__ out, int S)
{
    __shared__ float t[32][33];
    int n  = blockIdx.y;
    int s0 = blockIdx.x * 32;
    const float* pin = in + (size_t)n * 32 * S;
    #pragma unroll
    for (int c = threadIdx.y; c < 32; c += 8) {
        t[c][threadIdx.x] = pin[(size_t)c * S + s0 + threadIdx.x];
    }
    __syncthreads();
    float* pout = out + (size_t)n * S * 32;
    #pragma unroll
    for (int r = threadIdx.y; r < 32; r += 8) {
        pout[(size_t)(s0 + r) * 32 + threadIdx.x] = t[threadIdx.x][r];
    }
}

// ---------------------------------------------------------------------------
// bf16 helpers (RNE)
// ---------------------------------------------------------------------------
__device__ __forceinline__ short f2bf(float x) {
    unsigned u = __float_as_uint(x);
    unsigned r = (u + 0x7fffu + ((u >> 16) & 1u)) >> 16;
    return (short)r;
}
__device__ __forceinline__ bf16x8 cvt8(const float* __restrict__ p) {
    float4 a = *(const float4*)p;
    float4 b = *(const float4*)(p + 4);
    bf16x8 r;
    r[0] = f2bf(a.x); r[1] = f2bf(a.y); r[2] = f2bf(a.z); r[3] = f2bf(a.w);
    r[4] = f2bf(b.x); r[5] = f2bf(b.y); r[6] = f2bf(b.z); r[7] = f2bf(b.w);
    return r;
}

// ---------------------------------------------------------------------------
// MFMA proj GEMM: P[r][j] = sum_k Q[r][k]*W[j][k] + b[j]
// W = [W_off (256 rows) ; W_attn (128 rows)], K = 256, N = 384, M = 20400
// block = 256 thr (4 waves), tile BM=64 x BN=128; wave = 32x64 (2x4 frags).
// ---------------------------------------------------------------------------
__global__ __launch_bounds__(256) void proj_gemm_mfma(
    const float* __restrict__ Q,
    const float* __restrict__ Woff, const float* __restrict__ boff,
    const float* __restrict__ Wattn, const float* __restrict__ battn,
    float* __restrict__ P, int M)
{
    int tid  = threadIdx.x;
    int wave = tid >> 6;
    int lane = tid & 63;
    int bm = blockIdx.y * 64;           // grid.y: 319 row-blocks
    int bn = blockIdx.x * 128;          // grid.x: 3 col-blocks (n fastest)
    int wm = (wave & 1) * 32;
    int wn = (wave >> 1) * 64;
    int lr = lane & 15;
    int lk = (lane >> 4) * 8;

    f32x4 acc[2][4] = {};
    for (int k0 = 0; k0 < 256; k0 += 32) {
        bf16x8 afrag[2], bfrag[4];
        #pragma unroll
        for (int i = 0; i < 2; ++i) {
            int row = bm + wm + i * 16 + lr;
            row = row < M ? row : M - 1;         // clamp; stores are guarded
            afrag[i] = cvt8(Q + (size_t)row * 256 + k0 + lk);
        }
        #pragma unroll
        for (int j = 0; j < 4; ++j) {
            int n = bn + wn + j * 16 + lr;
            const float* wp = (n < 256) ? (Woff + (size_t)n * 256)
                                        : (Wattn + (size_t)(n - 256) * 256);
            bfrag[j] = cvt8(wp + k0 + lk);
        }
        #pragma unroll
        for (int i = 0; i < 2; ++i)
            #pragma unroll
            for (int j = 0; j < 4; ++j)
                acc[i][j] = __builtin_amdgcn_mfma_f32_16x16x32_bf16(
                    afrag[i], bfrag[j], acc[i][j], 0, 0, 0);
    }

    #pragma unroll
    for (int i = 0; i < 2; ++i) {
        int mbase = bm + wm + i * 16 + (lane >> 4) * 4;
        #pragma unroll
        for (int j = 0; j < 4; ++j) {
            int n = bn + wn + j * 16 + (lane & 15);
            float bias = (n < 256) ? boff[n] : battn[n - 256];
            #pragma unroll
            for (int r = 0; r < 4; ++r) {
                int row = mbase + r;
                if (row < M) P[(size_t)row * 384 + n] = acc[i][j][r] + bias;
            }
        }
    }
}

// ---------------------------------------------------------------------------
// select element (idx in 0..3) of a float4 via cndmask chain (no scratch)
// ---------------------------------------------------------------------------
__device__ __forceinline__ float sel4(float4 v, int idx) {
    float r = v.x;
    r = (idx == 1) ? v.y : r;
    r = (idx == 2) ? v.z : r;
    r = (idx == 3) ? v.w : r;
    return r;
}

// ---------------------------------------------------------------------------
// sampling + softmax + weighted sum. one block (256 thr) per (b, q).
// phase 1 (tid<128, tid=(lp,h) with h low): corner idx + attn-folded weights.
//   per-thread softmax on named float4 regs (NO runtime-indexed arrays ->
//   no scratch; round-6/7's g[lp] cost 167 MB of scratch writes).
//   corner table row r = lp*8 + h, 12-dword row -> phase-2 reads conflict-free.
// phase 2: tid = (l, h, c4); per-p: 2 LDS int4 reads + 4 float4 gathers + FMA.
// ---------------------------------------------------------------------------
__global__ __launch_bounds__(256) void ms_deform_kernel(
    const float* __restrict__ rp,     // (BS, NQ, L, NK, 2)
    const float* __restrict__ proj,   // (BS*LEN_Q, 384)
    const float* __restrict__ vt,     // transposed values, all levels
    float* __restrict__ out)          // (BS, LEN_Q, 256)
{
    int bq = blockIdx.x;
    int b  = bq / LEN_Q;
    int q  = bq - b * LEN_Q;
    int qi = q / NK;
    int ki = q - qi * NK;

    __shared__ int   s_iw[128][12];   // row r=lp*8+h: dwords 0..7 = 4x(idx,w)
    __shared__ float4 s_red[256];

    int tid = threadIdx.x;
    const float* prow = proj + (size_t)bq * 384;

    if (tid < 128) {
        int h  = tid & 7;
        int lp = tid >> 3;            // 0..15
        int l  = lp >> 2;
        int p  = lp & 3;
        int Wl = 128 >> l;            // square levels: 128,64,32,16
        float ww = (float)Wl;

        size_t rbase = ((((size_t)b * NQ + qi) * N_LEVELS + l) * NK + ki) * 2;
        float rx = rp[rbase + 0];
        float ry = rp[rbase + 1];
        int oj = ((h * N_LEVELS + l) * N_POINTS + p) * 2;
        float ox = prow[oj], oy = prow[oj + 1];
        // grid_sample align_corners=False: x = loc*w - 0.5
        float x = (rx + ox / ww) * ww - 0.5f;
        float y = (ry + oy / ww) * ww - 0.5f;
        float x0f = floorf(x), y0f = floorf(y);
        float wx1 = x - x0f, wy1 = y - y0f;
        float wx0 = 1.f - wx1, wy0 = 1.f - wy1;
        int x0 = (int)x0f, y0 = (int)y0f;

        // per-thread softmax weight for element (h, lp) — named regs only
        const float* lg = prow + 256 + h * 16;
        float4 g0 = *(const float4*)(lg + 0);
        float4 g1 = *(const float4*)(lg + 4);
        float4 g2 = *(const float4*)(lg + 8);
        float4 g3 = *(const float4*)(lg + 12);
        float mx = fmaxf(
            fmaxf(fmaxf(fmaxf(g0.x, g0.y), fmaxf(g0.z, g0.w)),
                  fmaxf(fmaxf(g1.x, g1.y), fmaxf(g1.z, g1.w))),
            fmaxf(fmaxf(fmaxf(g2.x, g2.y), fmaxf(g2.z, g2.w)),
                  fmaxf(fmaxf(g3.x, g3.y), fmaxf(g3.z, g3.w))));
        float sum =
            __expf(g0.x - mx) + __expf(g0.y - mx) + __expf(g0.z - mx) + __expf(g0.w - mx) +
            __expf(g1.x - mx) + __expf(g1.y - mx) + __expf(g1.z - mx) + __expf(g1.w - mx) +
            __expf(g2.x - mx) + __expf(g2.y - mx) + __expf(g2.z - mx) + __expf(g2.w - mx) +
            __expf(g3.x - mx) + __expf(g3.y - mx) + __expf(g3.z - mx) + __expf(g3.w - mx);
        float4 gsel = g0;
        gsel = (l == 1) ? g1 : gsel;
        gsel = (l == 2) ? g2 : gsel;
        gsel = (l == 3) ? g3 : gsel;
        float glp = sel4(gsel, p);
        float a = __expf(glp - mx) / sum;

        int r = lp * 8 + h;
        #pragma unroll
        for (int corner = 0; corner < 4; ++corner) {
            int xi = x0 + (corner & 1);
            int yi = y0 + (corner >> 1);
            float wgt = ((corner & 1) ? wx1 : wx0) * ((corner >> 1) ? wy1 : wy0);
            bool valid = (xi >= 0) && (xi < Wl) && (yi >= 0) && (yi < Wl);
            int2 iw;
            iw.x = valid ? (yi * Wl + xi) * HD : 0;
            iw.y = __float_as_int(valid ? wgt * a : 0.f);
            *(int2*)&s_iw[r][corner * 2] = iw;
        }
    }
    __syncthreads();

    // phase 2: tid = l*64 + h*8 + c4
    int l  = tid >> 6;
    int h  = (tid >> 3) & 7;
    int c4 = tid & 7;
    int n  = b * N_HEADS + h;
    const size_t lb[4]  = {LB0, LB1, LB2, LB3};
    const int    Ssz[4] = {16384, 4096, 1024, 256};

    const float* vbase = vt + lb[l] + (size_t)n * Ssz[l] * HD + c4 * 4;
    int rb = l * 32 + h;                 // r = (l*4+p)*8 + h

    float4 acc = make_float4(0.f, 0.f, 0.f, 0.f);
    #pragma unroll
    for (int p = 0; p < 4; ++p) {
        int4 A  = *(const int4*)&s_iw[rb + p * 8][0];   // corners 0,1
        int4 Bv = *(const int4*)&s_iw[rb + p * 8][4];   // corners 2,3
        float4 v0 = *(const float4*)(vbase + A.x);
        float4 v1 = *(const float4*)(vbase + A.z);
        float4 v2 = *(const float4*)(vbase + Bv.x);
        float4 v3 = *(const float4*)(vbase + Bv.z);
        float w0 = __int_as_float(A.y);
        float w1 = __int_as_float(A.w);
        float w2 = __int_as_float(Bv.y);
        float w3 = __int_as_float(Bv.w);
        acc.x += w0 * v0.x + w1 * v1.x + w2 * v2.x + w3 * v3.x;
        acc.y += w0 * v0.y + w1 * v1.y + w2 * v2.y + w3 * v3.y;
        acc.z += w0 * v0.z + w1 * v1.z + w2 * v2.z + w3 * v3.z;
        acc.w += w0 * v0.w + w1 * v1.w + w2 * v2.w + w3 * v3.w;
    }

    s_red[tid] = acc;
    __syncthreads();
    if (tid < 64) {
        float4 a0 = s_red[tid];
        float4 a1 = s_red[tid + 64];
        float4 a2 = s_red[tid + 128];
        float4 a3 = s_red[tid + 192];
        float4 o;
        o.x = a0.x + a1.x + a2.x + a3.x;
        o.y = a0.y + a1.y + a2.y + a3.y;
        o.z = a0.z + a1.z + a2.z + a3.z;
        o.w = a0.w + a1.w + a2.w + a3.w;
        // tid = h*8 + c4 -> channel offset = h*32 + c4*4 = tid*4
        *(float4*)(out + (size_t)bq * 256 + tid * 4) = o;
    }
}

// ---------------------------------------------------------------------------
extern "C" void kernel_launch(void* const* d_in, const int* in_sizes, int n_in,
                              void* d_out, int out_size, void* d_ws, size_t ws_size,
                              hipStream_t stream)
{
    const float* query = (const float*)d_in[0];
    const float* refp  = (const float*)d_in[1];
    const float* v0    = (const float*)d_in[2];
    const float* v1    = (const float*)d_in[3];
    const float* v2    = (const float*)d_in[4];
    const float* v3    = (const float*)d_in[5];
    const float* Woff  = (const float*)d_in[6];
    const float* boff  = (const float*)d_in[7];
    const float* Wattn = (const float*)d_in[8];
    const float* battn = (const float*)d_in[9];
    float* out  = (float*)d_out;
    float* vt   = (float*)d_ws;
    float* proj = vt + PROJ_OFF;

    // 1) transpose values to (n, s, c)
    transpose_kernel<<<dim3(16384 / 32, 32), dim3(32, 8), 0, stream>>>(v0, vt + LB0, 16384);
    transpose_kernel<<<dim3(4096  / 32, 32), dim3(32, 8), 0, stream>>>(v1, vt + LB1, 4096);
    transpose_kernel<<<dim3(1024  / 32, 32), dim3(32, 8), 0, stream>>>(v2, vt + LB2, 1024);
    transpose_kernel<<<dim3(256   / 32, 32), dim3(32, 8), 0, stream>>>(v3, vt + LB3, 256);

    // 2) fused projection MFMA GEMM -> (M, 384) = [off(256) | attn_logits(128)]
    int M = BS * LEN_Q;                       // 20400
    proj_gemm_mfma<<<dim3(3, (M + 63) / 64), 256, 0, stream>>>(
        query, Woff, boff, Wattn, battn, proj, M);

    // 3) sampling + softmax + weighted reduction
    ms_deform_kernel<<<M, 256, 0, stream>>>(refp, proj, vt, out);
}

// Round 9
// 152.766 us; speedup vs baseline: 1.3653x; 1.3653x over previous
//
#include <hip/hip_runtime.h>
#include <math.h>

#define BS        4
#define NQ        300
#define NK        17
#define LEN_Q     5100          // NQ*NK
#define N_HEADS   8
#define N_LEVELS  4
#define N_POINTS  4
#define D_MODEL   256
#define HD        32            // D_MODEL / N_HEADS

// transposed-value level bases (floats), layout vt[l][n][s][c], c contiguous
#define LB0 0
#define LB1 16777216            // + 32*16384*32
#define LB2 20971520            // + 32*4096*32
#define LB3 22020096            // + 32*1024*32
#define VT_TOTAL 22282240       // + 32*256*32
#define PROJ_OFF VT_TOTAL       // proj: (BS*LEN_Q, 384) floats

typedef __attribute__((ext_vector_type(8))) short bf16x8;
typedef __attribute__((ext_vector_type(4))) float f32x4;

// ---------------------------------------------------------------------------
// 32xS -> Sx32 transpose per n (classic LDS tile). block (32,8), grid (S/32, 32)
// ---------------------------------------------------------------------------
__global__ __launch_bounds__(256) void transpose_kernel(
    const float* __restrict__ in, float* __restrict__ out, int S)
{
    __shared__ float t[32][33];
    int n  = blockIdx.y;
    int s0 = blockIdx.x * 32;
    const float* pin = in + (size_t)n * 32 * S;
    #pragma unroll
    for (int c = threadIdx.y; c < 32; c += 8) {
        t[c][threadIdx.x] = pin[(size_t)c * S + s0 + threadIdx.x];
    }
    __syncthreads();
    float* pout = out + (size_t)n * S * 32;
    #pragma unroll
    for (int r = threadIdx.y; r < 32; r += 8) {
        pout[(size_t)(s0 + r) * 32 + threadIdx.x] = t[threadIdx.x][r];
    }
}

// ---------------------------------------------------------------------------
// bf16 helpers (RNE)
// ---------------------------------------------------------------------------
__device__ __forceinline__ short f2bf(float x) {
    unsigned u = __float_as_uint(x);
    unsigned r = (u + 0x7fffu + ((u >> 16) & 1u)) >> 16;
    return (short)r;
}
__device__ __forceinline__ bf16x8 cvt8(const float* __restrict__ p) {
    float4 a = *(const float4*)p;
    float4 b = *(const float4*)(p + 4);
    bf16x8 r;
    r[0] = f2bf(a.x); r[1] = f2bf(a.y); r[2] = f2bf(a.z); r[3] = f2bf(a.w);
    r[4] = f2bf(b.x); r[5] = f2bf(b.y); r[6] = f2bf(b.z); r[7] = f2bf(b.w);
    return r;
}

// ---------------------------------------------------------------------------
// MFMA proj GEMM: P[r][j] = sum_k Q[r][k]*W[j][k] + b[j]
// W = [W_off (256 rows) ; W_attn (128 rows)], K = 256, N = 384, M = 20400
// block = 256 thr (4 waves), tile BM=64 x BN=128; wave = 32x64 (2x4 frags).
// ---------------------------------------------------------------------------
__global__ __launch_bounds__(256) void proj_gemm_mfma(
    const float* __restrict__ Q,
    const float* __restrict__ Woff, const float* __restrict__ boff,
    const float* __restrict__ Wattn, const float* __restrict__ battn,
    float* __restrict__ P, int M)
{
    int tid  = threadIdx.x;
    int wave = tid >> 6;
    int lane = tid & 63;
    int bm = blockIdx.y * 64;           // grid.y: 319 row-blocks
    int bn = blockIdx.x * 128;          // grid.x: 3 col-blocks (n fastest)
    int wm = (wave & 1) * 32;
    int wn = (wave >> 1) * 64;
    int lr = lane & 15;
    int lk = (lane >> 4) * 8;

    f32x4 acc[2][4] = {};
    for (int k0 = 0; k0 < 256; k0 += 32) {
        bf16x8 afrag[2], bfrag[4];
        #pragma unroll
        for (int i = 0; i < 2; ++i) {
            int row = bm + wm + i * 16 + lr;
            row = row < M ? row : M - 1;         // clamp; stores are guarded
            afrag[i] = cvt8(Q + (size_t)row * 256 + k0 + lk);
        }
        #pragma unroll
        for (int j = 0; j < 4; ++j) {
            int n = bn + wn + j * 16 + lr;
            const float* wp = (n < 256) ? (Woff + (size_t)n * 256)
                                        : (Wattn + (size_t)(n - 256) * 256);
            bfrag[j] = cvt8(wp + k0 + lk);
        }
        #pragma unroll
        for (int i = 0; i < 2; ++i)
            #pragma unroll
            for (int j = 0; j < 4; ++j)
                acc[i][j] = __builtin_amdgcn_mfma_f32_16x16x32_bf16(
                    afrag[i], bfrag[j], acc[i][j], 0, 0, 0);
    }

    #pragma unroll
    for (int i = 0; i < 2; ++i) {
        int mbase = bm + wm + i * 16 + (lane >> 4) * 4;
        #pragma unroll
        for (int j = 0; j < 4; ++j) {
            int n = bn + wn + j * 16 + (lane & 15);
            float bias = (n < 256) ? boff[n] : battn[n - 256];
            #pragma unroll
            for (int r = 0; r < 4; ++r) {
                int row = mbase + r;
                if (row < M) P[(size_t)row * 384 + n] = acc[i][j][r] + bias;
            }
        }
    }
}

// ---------------------------------------------------------------------------
// sampling + softmax + weighted sum. one block (256 thr) per (b, q).
// phase 0 (tid<128, tid=(h',lp') h' high): wave-shuffle softmax, 16 logits
//   live on 16 consecutive lanes -> shfl_xor width 16; ~6 live regs, no spill.
// phase 1 (tid<128, tid=(lp,h) h low): corner idx + attn-folded weights into
//   s_iw[tid] (row r=lp*8+h, 12-dword rows -> phase-2 reads conflict-free).
// phase 2: tid = (l, h, c4); per-p: 2 LDS int4 reads + 4 float4 gathers + FMA.
// ---------------------------------------------------------------------------
__global__ __launch_bounds__(256) void ms_deform_kernel(
    const float* __restrict__ rp,     // (BS, NQ, L, NK, 2)
    const float* __restrict__ proj,   // (BS*LEN_Q, 384)
    const float* __restrict__ vt,     // transposed values, all levels
    float* __restrict__ out)          // (BS, LEN_Q, 256)
{
    int bq = blockIdx.x;
    int b  = bq / LEN_Q;
    int q  = bq - b * LEN_Q;
    int qi = q / NK;
    int ki = q - qi * NK;

    __shared__ int   s_iw[128][12];   // row r=lp*8+h: dwords 0..7 = 4x(idx,w)
    __shared__ float s_attn[128];     // [h*16+lp]
    __shared__ float4 s_red[256];

    int tid = threadIdx.x;
    const float* prow = proj + (size_t)bq * 384;

    // phase 0: softmax weight for element (h'=tid>>4, lp'=tid&15)
    if (tid < 128) {
        float g = prow[256 + tid];            // coalesced: 128 consecutive
        float mx = g;
        mx = fmaxf(mx, __shfl_xor(mx, 1, 16));
        mx = fmaxf(mx, __shfl_xor(mx, 2, 16));
        mx = fmaxf(mx, __shfl_xor(mx, 4, 16));
        mx = fmaxf(mx, __shfl_xor(mx, 8, 16));
        float e = __expf(g - mx);
        float s = e;
        s += __shfl_xor(s, 1, 16);
        s += __shfl_xor(s, 2, 16);
        s += __shfl_xor(s, 4, 16);
        s += __shfl_xor(s, 8, 16);
        s_attn[tid] = e / s;
    }
    __syncthreads();

    // phase 1: corners for element (h=tid&7, lp=tid>>3)
    if (tid < 128) {
        int h  = tid & 7;
        int lp = tid >> 3;            // 0..15
        int l  = lp >> 2;
        int p  = lp & 3;
        int Wl = 128 >> l;            // square levels: 128,64,32,16
        float ww = (float)Wl;

        size_t rbase = ((((size_t)b * NQ + qi) * N_LEVELS + l) * NK + ki) * 2;
        float rx = rp[rbase + 0];
        float ry = rp[rbase + 1];
        int oj = ((h * N_LEVELS + l) * N_POINTS + p) * 2;
        float ox = prow[oj], oy = prow[oj + 1];
        // grid_sample align_corners=False: x = loc*w - 0.5
        float x = (rx + ox / ww) * ww - 0.5f;
        float y = (ry + oy / ww) * ww - 0.5f;
        float x0f = floorf(x), y0f = floorf(y);
        float wx1 = x - x0f, wy1 = y - y0f;
        float wx0 = 1.f - wx1, wy0 = 1.f - wy1;
        int x0 = (int)x0f, y0 = (int)y0f;

        float a = s_attn[h * 16 + lp];

        // r = lp*8 + h == tid (since tid = lp*8 + h with this mapping)
        #pragma unroll
        for (int corner = 0; corner < 4; ++corner) {
            int xi = x0 + (corner & 1);
            int yi = y0 + (corner >> 1);
            float wgt = ((corner & 1) ? wx1 : wx0) * ((corner >> 1) ? wy1 : wy0);
            bool valid = (xi >= 0) && (xi < Wl) && (yi >= 0) && (yi < Wl);
            int2 iw;
            iw.x = valid ? (yi * Wl + xi) * HD : 0;
            iw.y = __float_as_int(valid ? wgt * a : 0.f);
            *(int2*)&s_iw[tid][corner * 2] = iw;
        }
    }
    __syncthreads();

    // phase 2: tid = l*64 + h*8 + c4
    int l  = tid >> 6;
    int h  = (tid >> 3) & 7;
    int c4 = tid & 7;
    int n  = b * N_HEADS + h;
    const size_t lb[4]  = {LB0, LB1, LB2, LB3};
    const int    Ssz[4] = {16384, 4096, 1024, 256};

    const float* vbase = vt + lb[l] + (size_t)n * Ssz[l] * HD + c4 * 4;
    int rb = l * 32 + h;                 // r = (l*4+p)*8 + h

    float4 acc = make_float4(0.f, 0.f, 0.f, 0.f);
    #pragma unroll
    for (int p = 0; p < 4; ++p) {
        int4 A  = *(const int4*)&s_iw[rb + p * 8][0];   // corners 0,1
        int4 Bv = *(const int4*)&s_iw[rb + p * 8][4];   // corners 2,3
        float4 v0 = *(const float4*)(vbase + A.x);
        float4 v1 = *(const float4*)(vbase + A.z);
        float4 v2 = *(const float4*)(vbase + Bv.x);
        float4 v3 = *(const float4*)(vbase + Bv.z);
        float w0 = __int_as_float(A.y);
        float w1 = __int_as_float(A.w);
        float w2 = __int_as_float(Bv.y);
        float w3 = __int_as_float(Bv.w);
        acc.x += w0 * v0.x + w1 * v1.x + w2 * v2.x + w3 * v3.x;
        acc.y += w0 * v0.y + w1 * v1.y + w2 * v2.y + w3 * v3.y;
        acc.z += w0 * v0.z + w1 * v1.z + w2 * v2.z + w3 * v3.z;
        acc.w += w0 * v0.w + w1 * v1.w + w2 * v2.w + w3 * v3.w;
    }

    s_red[tid] = acc;
    __syncthreads();
    if (tid < 64) {
        float4 a0 = s_red[tid];
        float4 a1 = s_red[tid + 64];
        float4 a2 = s_red[tid + 128];
        float4 a3 = s_red[tid + 192];
        float4 o;
        o.x = a0.x + a1.x + a2.x + a3.x;
        o.y = a0.y + a1.y + a2.y + a3.y;
        o.z = a0.z + a1.z + a2.z + a3.z;
        o.w = a0.w + a1.w + a2.w + a3.w;
        // tid = h*8 + c4 -> channel offset = h*32 + c4*4 = tid*4
        *(float4*)(out + (size_t)bq * 256 + tid * 4) = o;
    }
}

// ---------------------------------------------------------------------------
extern "C" void kernel_launch(void* const* d_in, const int* in_sizes, int n_in,
                              void* d_out, int out_size, void* d_ws, size_t ws_size,
                              hipStream_t stream)
{
    const float* query = (const float*)d_in[0];
    const float* refp  = (const float*)d_in[1];
    const float* v0    = (const float*)d_in[2];
    const float* v1    = (const float*)d_in[3];
    const float* v2    = (const float*)d_in[4];
    const float* v3    = (const float*)d_in[5];
    const float* Woff  = (const float*)d_in[6];
    const float* boff  = (const float*)d_in[7];
    const float* Wattn = (const float*)d_in[8];
    const float* battn = (const float*)d_in[9];
    float* out  = (float*)d_out;
    float* vt   = (float*)d_ws;
    float* proj = vt + PROJ_OFF;

    // 1) transpose values to (n, s, c)
    transpose_kernel<<<dim3(16384 / 32, 32), dim3(32, 8), 0, stream>>>(v0, vt + LB0, 16384);
    transpose_kernel<<<dim3(4096  / 32, 32), dim3(32, 8), 0, stream>>>(v1, vt + LB1, 4096);
    transpose_kernel<<<dim3(1024  / 32, 32), dim3(32, 8), 0, stream>>>(v2, vt + LB2, 1024);
    transpose_kernel<<<dim3(256   / 32, 32), dim3(32, 8), 0, stream>>>(v3, vt + LB3, 256);

    // 2) fused projection MFMA GEMM -> (M, 384) = [off(256) | attn_logits(128)]
    int M = BS * LEN_Q;                       // 20400
    proj_gemm_mfma<<<dim3(3, (M + 63) / 64), 256, 0, stream>>>(
        query, Woff, boff, Wattn, battn, proj, M);

    // 3) sampling + softmax + weighted reduction
    ms_deform_kernel<<<M, 256, 0, stream>>>(refp, proj, vt, out);
}

// Round 10
// 131.889 us; speedup vs baseline: 1.5814x; 1.1583x over previous
//
#include <hip/hip_runtime.h>
#include <math.h>

#define BS        4
#define NQ        300
#define NK        17
#define LEN_Q     5100          // NQ*NK
#define N_HEADS   8
#define N_LEVELS  4
#define N_POINTS  4
#define D_MODEL   256
#define HD        32            // D_MODEL / N_HEADS

// transposed-value level bases (ushort/bf16 units), layout vt[l][n][s][c]
#define LB0 0
#define LB1 16777216            // + 32*16384*32
#define LB2 20971520            // + 32*4096*32
#define LB3 22020096            // + 32*1024*32
#define VT_TOTAL 22282240       // ushorts (44.6 MB)

typedef __attribute__((ext_vector_type(8))) short bf16x8;
typedef __attribute__((ext_vector_type(4))) float f32x4;

// ---------------------------------------------------------------------------
// bf16 helpers (RNE)
// ---------------------------------------------------------------------------
__device__ __forceinline__ unsigned short f2bf(float x) {
    unsigned u = __float_as_uint(x);
    unsigned r = (u + 0x7fffu + ((u >> 16) & 1u)) >> 16;
    return (unsigned short)r;
}
__device__ __forceinline__ float bf2f(unsigned short s) {
    return __uint_as_float((unsigned)s << 16);
}
__device__ __forceinline__ bf16x8 cvt8(const float* __restrict__ p) {
    float4 a = *(const float4*)p;
    float4 b = *(const float4*)(p + 4);
    bf16x8 r;
    r[0] = f2bf(a.x); r[1] = f2bf(a.y); r[2] = f2bf(a.z); r[3] = f2bf(a.w);
    r[4] = f2bf(b.x); r[5] = f2bf(b.y); r[6] = f2bf(b.z); r[7] = f2bf(b.w);
    return r;
}

// ---------------------------------------------------------------------------
// fused transpose all levels: (n, 32, S) fp32 -> (n, S, 32) bf16.
// block (32,8); grid.x = 512+128+32+8 = 680 tiles, grid.y = 32 (n).
// ---------------------------------------------------------------------------
__global__ __launch_bounds__(256) void transpose_bf16_kernel(
    const float* __restrict__ v0, const float* __restrict__ v1,
    const float* __restrict__ v2, const float* __restrict__ v3,
    unsigned short* __restrict__ vt)
{
    __shared__ float t[32][33];
    int bx = blockIdx.x;
    int n  = blockIdx.y;

    const float* in; int S; size_t ob; int tile;
    if (bx < 512)      { in = v0; S = 16384; ob = LB0; tile = bx; }
    else if (bx < 640) { in = v1; S = 4096;  ob = LB1; tile = bx - 512; }
    else if (bx < 672) { in = v2; S = 1024;  ob = LB2; tile = bx - 640; }
    else               { in = v3; S = 256;   ob = LB3; tile = bx - 672; }

    int s0 = tile * 32;
    const float* pin = in + (size_t)n * 32 * S;
    #pragma unroll
    for (int c = threadIdx.y; c < 32; c += 8) {
        t[c][threadIdx.x] = pin[(size_t)c * S + s0 + threadIdx.x];
    }
    __syncthreads();
    unsigned short* pout = vt + ob + (size_t)n * S * 32;
    #pragma unroll
    for (int r = threadIdx.y; r < 32; r += 8) {
        pout[(size_t)(s0 + r) * 32 + threadIdx.x] = f2bf(t[threadIdx.x][r]);
    }
}

// ---------------------------------------------------------------------------
// MFMA proj GEMM: P[r][j] = sum_k Q[r][k]*W[j][k] + b[j]
// W = [W_off (256 rows) ; W_attn (128 rows)], K = 256, N = 384, M = 20400
// block = 256 thr (4 waves), tile BM=64 x BN=128; wave = 32x64 (2x4 frags).
// ---------------------------------------------------------------------------
__global__ __launch_bounds__(256) void proj_gemm_mfma(
    const float* __restrict__ Q,
    const float* __restrict__ Woff, const float* __restrict__ boff,
    const float* __restrict__ Wattn, const float* __restrict__ battn,
    float* __restrict__ P, int M)
{
    int tid  = threadIdx.x;
    int wave = tid >> 6;
    int lane = tid & 63;
    int bm = blockIdx.y * 64;           // grid.y: 319 row-blocks
    int bn = blockIdx.x * 128;          // grid.x: 3 col-blocks (n fastest)
    int wm = (wave & 1) * 32;
    int wn = (wave >> 1) * 64;
    int lr = lane & 15;
    int lk = (lane >> 4) * 8;

    f32x4 acc[2][4] = {};
    for (int k0 = 0; k0 < 256; k0 += 32) {
        bf16x8 afrag[2], bfrag[4];
        #pragma unroll
        for (int i = 0; i < 2; ++i) {
            int row = bm + wm + i * 16 + lr;
            row = row < M ? row : M - 1;         // clamp; stores are guarded
            afrag[i] = cvt8(Q + (size_t)row * 256 + k0 + lk);
        }
        #pragma unroll
        for (int j = 0; j < 4; ++j) {
            int n = bn + wn + j * 16 + lr;
            const float* wp = (n < 256) ? (Woff + (size_t)n * 256)
                                        : (Wattn + (size_t)(n - 256) * 256);
            bfrag[j] = cvt8(wp + k0 + lk);
        }
        #pragma unroll
        for (int i = 0; i < 2; ++i)
            #pragma unroll
            for (int j = 0; j < 4; ++j)
                acc[i][j] = __builtin_amdgcn_mfma_f32_16x16x32_bf16(
                    afrag[i], bfrag[j], acc[i][j], 0, 0, 0);
    }

    #pragma unroll
    for (int i = 0; i < 2; ++i) {
        int mbase = bm + wm + i * 16 + (lane >> 4) * 4;
        #pragma unroll
        for (int j = 0; j < 4; ++j) {
            int n = bn + wn + j * 16 + (lane & 15);
            float bias = (n < 256) ? boff[n] : battn[n - 256];
            #pragma unroll
            for (int r = 0; r < 4; ++r) {
                int row = mbase + r;
                if (row < M) P[(size_t)row * 384 + n] = acc[i][j][r] + bias;
            }
        }
    }
}

// ---------------------------------------------------------------------------
// sampling + softmax + weighted sum. one block (256 thr) per (b, q).
// phase 0 (tid<128): wave-shuffle softmax (16 logits on 16 lanes, no spill).
// phase 1 (tid<128, tid=(lp,h) h low): corner idx + attn-folded weights into
//   s_iw[tid] (12-dword rows -> phase-2 reads conflict-free).
// phase 2: tid = (l, h, c4); per-p: 2 LDS int4 reads + 4 bf16x4 gathers
//   (8 B each, shift-convert) + FMA; LDS-reduce over l; float4 store.
// ---------------------------------------------------------------------------
__global__ __launch_bounds__(256) void ms_deform_kernel(
    const float* __restrict__ rp,            // (BS, NQ, L, NK, 2)
    const float* __restrict__ proj,          // (BS*LEN_Q, 384)
    const unsigned short* __restrict__ vt,   // transposed bf16 values
    float* __restrict__ out)                 // (BS, LEN_Q, 256)
{
    int bq = blockIdx.x;
    int b  = bq / LEN_Q;
    int q  = bq - b * LEN_Q;
    int qi = q / NK;
    int ki = q - qi * NK;

    __shared__ int   s_iw[128][12];   // row r=lp*8+h: dwords 0..7 = 4x(idx,w)
    __shared__ float s_attn[128];     // [h*16+lp]
    __shared__ float4 s_red[256];

    int tid = threadIdx.x;
    const float* prow = proj + (size_t)bq * 384;

    // phase 0: softmax weight for element (h'=tid>>4, lp'=tid&15)
    if (tid < 128) {
        float g = prow[256 + tid];            // coalesced: 128 consecutive
        float mx = g;
        mx = fmaxf(mx, __shfl_xor(mx, 1, 16));
        mx = fmaxf(mx, __shfl_xor(mx, 2, 16));
        mx = fmaxf(mx, __shfl_xor(mx, 4, 16));
        mx = fmaxf(mx, __shfl_xor(mx, 8, 16));
        float e = __expf(g - mx);
        float s = e;
        s += __shfl_xor(s, 1, 16);
        s += __shfl_xor(s, 2, 16);
        s += __shfl_xor(s, 4, 16);
        s += __shfl_xor(s, 8, 16);
        s_attn[tid] = e / s;
    }
    __syncthreads();

    // phase 1: corners for element (h=tid&7, lp=tid>>3)
    if (tid < 128) {
        int h  = tid & 7;
        int lp = tid >> 3;            // 0..15
        int l  = lp >> 2;
        int p  = lp & 3;
        int Wl = 128 >> l;            // square levels: 128,64,32,16
        float ww = (float)Wl;

        size_t rbase = ((((size_t)b * NQ + qi) * N_LEVELS + l) * NK + ki) * 2;
        float rx = rp[rbase + 0];
        float ry = rp[rbase + 1];
        int oj = ((h * N_LEVELS + l) * N_POINTS + p) * 2;
        float ox = prow[oj], oy = prow[oj + 1];
        // grid_sample align_corners=False: x = loc*w - 0.5
        float x = (rx + ox / ww) * ww - 0.5f;
        float y = (ry + oy / ww) * ww - 0.5f;
        float x0f = floorf(x), y0f = floorf(y);
        float wx1 = x - x0f, wy1 = y - y0f;
        float wx0 = 1.f - wx1, wy0 = 1.f - wy1;
        int x0 = (int)x0f, y0 = (int)y0f;

        float a = s_attn[h * 16 + lp];

        // r = lp*8 + h == tid with this mapping
        #pragma unroll
        for (int corner = 0; corner < 4; ++corner) {
            int xi = x0 + (corner & 1);
            int yi = y0 + (corner >> 1);
            float wgt = ((corner & 1) ? wx1 : wx0) * ((corner >> 1) ? wy1 : wy0);
            bool valid = (xi >= 0) && (xi < Wl) && (yi >= 0) && (yi < Wl);
            int2 iw;
            iw.x = valid ? (yi * Wl + xi) * HD : 0;   // ushort-unit index
            iw.y = __float_as_int(valid ? wgt * a : 0.f);
            *(int2*)&s_iw[tid][corner * 2] = iw;
        }
    }
    __syncthreads();

    // phase 2: tid = l*64 + h*8 + c4
    int l  = tid >> 6;
    int h  = (tid >> 3) & 7;
    int c4 = tid & 7;
    int n  = b * N_HEADS + h;
    const size_t lb[4]  = {LB0, LB1, LB2, LB3};
    const int    Ssz[4] = {16384, 4096, 1024, 256};

    const unsigned short* vbase = vt + lb[l] + (size_t)n * Ssz[l] * HD + c4 * 4;
    int rb = l * 32 + h;                 // r = (l*4+p)*8 + h

    float4 acc = make_float4(0.f, 0.f, 0.f, 0.f);
    #pragma unroll
    for (int p = 0; p < 4; ++p) {
        int4 A  = *(const int4*)&s_iw[rb + p * 8][0];   // corners 0,1
        int4 Bv = *(const int4*)&s_iw[rb + p * 8][4];   // corners 2,3
        ushort4 u0 = *(const ushort4*)(vbase + A.x);
        ushort4 u1 = *(const ushort4*)(vbase + A.z);
        ushort4 u2 = *(const ushort4*)(vbase + Bv.x);
        ushort4 u3 = *(const ushort4*)(vbase + Bv.z);
        float w0 = __int_as_float(A.y);
        float w1 = __int_as_float(A.w);
        float w2 = __int_as_float(Bv.y);
        float w3 = __int_as_float(Bv.w);
        acc.x += w0 * bf2f(u0.x) + w1 * bf2f(u1.x) + w2 * bf2f(u2.x) + w3 * bf2f(u3.x);
        acc.y += w0 * bf2f(u0.y) + w1 * bf2f(u1.y) + w2 * bf2f(u2.y) + w3 * bf2f(u3.y);
        acc.z += w0 * bf2f(u0.z) + w1 * bf2f(u1.z) + w2 * bf2f(u2.z) + w3 * bf2f(u3.z);
        acc.w += w0 * bf2f(u0.w) + w1 * bf2f(u1.w) + w2 * bf2f(u2.w) + w3 * bf2f(u3.w);
    }

    s_red[tid] = acc;
    __syncthreads();
    if (tid < 64) {
        float4 a0 = s_red[tid];
        float4 a1 = s_red[tid + 64];
        float4 a2 = s_red[tid + 128];
        float4 a3 = s_red[tid + 192];
        float4 o;
        o.x = a0.x + a1.x + a2.x + a3.x;
        o.y = a0.y + a1.y + a2.y + a3.y;
        o.z = a0.z + a1.z + a2.z + a3.z;
        o.w = a0.w + a1.w + a2.w + a3.w;
        // tid = h*8 + c4 -> channel offset = h*32 + c4*4 = tid*4
        *(float4*)(out + (size_t)bq * 256 + tid * 4) = o;
    }
}

// ---------------------------------------------------------------------------
extern "C" void kernel_launch(void* const* d_in, const int* in_sizes, int n_in,
                              void* d_out, int out_size, void* d_ws, size_t ws_size,
                              hipStream_t stream)
{
    const float* query = (const float*)d_in[0];
    const float* refp  = (const float*)d_in[1];
    const float* v0    = (const float*)d_in[2];
    const float* v1    = (const float*)d_in[3];
    const float* v2    = (const float*)d_in[4];
    const float* v3    = (const float*)d_in[5];
    const float* Woff  = (const float*)d_in[6];
    const float* boff  = (const float*)d_in[7];
    const float* Wattn = (const float*)d_in[8];
    const float* battn = (const float*)d_in[9];
    float* out = (float*)d_out;
    unsigned short* vt = (unsigned short*)d_ws;
    float* proj = (float*)(vt + VT_TOTAL);    // 44.6 MB offset, 4B-aligned

    // 1) fused transpose all levels -> bf16 (n, s, c)
    transpose_bf16_kernel<<<dim3(680, 32), dim3(32, 8), 0, stream>>>(
        v0, v1, v2, v3, vt);

    // 2) fused projection MFMA GEMM -> (M, 384) = [off(256) | attn_logits(128)]
    int M = BS * LEN_Q;                       // 20400
    proj_gemm_mfma<<<dim3(3, (M + 63) / 64), 256, 0, stream>>>(
        query, Woff, boff, Wattn, battn, proj, M);

    // 3) sampling + softmax + weighted reduction
    ms_deform_kernel<<<M, 256, 0, stream>>>(refp, proj, vt, out);
}

// Round 11
// 129.136 us; speedup vs baseline: 1.6152x; 1.0213x over previous
//
#include <hip/hip_runtime.h>
#include <math.h>

#define BS        4
#define NQ        300
#define NK        17
#define LEN_Q     5100          // NQ*NK
#define N_HEADS   8
#define N_LEVELS  4
#define N_POINTS  4
#define D_MODEL   256
#define HD        32            // D_MODEL / N_HEADS

// transposed-value level bases (ushort/bf16 units), layout vt[l][n][s][c]
#define LB0 0
#define LB1 16777216            // + 32*16384*32
#define LB2 20971520            // + 32*4096*32
#define LB3 22020096            // + 32*1024*32
#define VT_TOTAL 22282240       // ushorts (44.6 MB)

typedef __attribute__((ext_vector_type(8))) short bf16x8;
typedef __attribute__((ext_vector_type(4))) float f32x4;

// ---------------------------------------------------------------------------
// bf16 helpers (RNE)
// ---------------------------------------------------------------------------
__device__ __forceinline__ unsigned short f2bf(float x) {
    unsigned u = __float_as_uint(x);
    unsigned r = (u + 0x7fffu + ((u >> 16) & 1u)) >> 16;
    return (unsigned short)r;
}
__device__ __forceinline__ float bf2f(unsigned short s) {
    return __uint_as_float((unsigned)s << 16);
}
__device__ __forceinline__ bf16x8 cvt8(const float* __restrict__ p) {
    float4 a = *(const float4*)p;
    float4 b = *(const float4*)(p + 4);
    bf16x8 r;
    r[0] = f2bf(a.x); r[1] = f2bf(a.y); r[2] = f2bf(a.z); r[3] = f2bf(a.w);
    r[4] = f2bf(b.x); r[5] = f2bf(b.y); r[6] = f2bf(b.z); r[7] = f2bf(b.w);
    return r;
}

// ---------------------------------------------------------------------------
// fused transpose all levels: (n, 32, S) fp32 -> (n, S, 32) bf16.
// block (32,8); grid.x = 512+128+32+8 = 680 tiles, grid.y = 32 (n).
// ---------------------------------------------------------------------------
__global__ __launch_bounds__(256) void transpose_bf16_kernel(
    const float* __restrict__ v0, const float* __restrict__ v1,
    const float* __restrict__ v2, const float* __restrict__ v3,
    unsigned short* __restrict__ vt)
{
    __shared__ float t[32][33];
    int bx = blockIdx.x;
    int n  = blockIdx.y;

    const float* in; int S; size_t ob; int tile;
    if (bx < 512)      { in = v0; S = 16384; ob = LB0; tile = bx; }
    else if (bx < 640) { in = v1; S = 4096;  ob = LB1; tile = bx - 512; }
    else if (bx < 672) { in = v2; S = 1024;  ob = LB2; tile = bx - 640; }
    else               { in = v3; S = 256;   ob = LB3; tile = bx - 672; }

    int s0 = tile * 32;
    const float* pin = in + (size_t)n * 32 * S;
    #pragma unroll
    for (int c = threadIdx.y; c < 32; c += 8) {
        t[c][threadIdx.x] = pin[(size_t)c * S + s0 + threadIdx.x];
    }
    __syncthreads();
    unsigned short* pout = vt + ob + (size_t)n * S * 32;
    #pragma unroll
    for (int r = threadIdx.y; r < 32; r += 8) {
        pout[(size_t)(s0 + r) * 32 + threadIdx.x] = f2bf(t[threadIdx.x][r]);
    }
}

// ---------------------------------------------------------------------------
// MFMA proj GEMM: P[r][j] = sum_k Q[r][k]*W[j][k] + b[j]
// W = [W_off (256 rows) ; W_attn (128 rows)], K = 256, N = 384, M = 20400
// block = 256 thr (4 waves), tile BM=64 x BN=128; wave = 32x64 (2x4 frags).
// ---------------------------------------------------------------------------
__global__ __launch_bounds__(256) void proj_gemm_mfma(
    const float* __restrict__ Q,
    const float* __restrict__ Woff, const float* __restrict__ boff,
    const float* __restrict__ Wattn, const float* __restrict__ battn,
    float* __restrict__ P, int M)
{
    int tid  = threadIdx.x;
    int wave = tid >> 6;
    int lane = tid & 63;
    int bm = blockIdx.y * 64;           // grid.y: 319 row-blocks
    int bn = blockIdx.x * 128;          // grid.x: 3 col-blocks (n fastest)
    int wm = (wave & 1) * 32;
    int wn = (wave >> 1) * 64;
    int lr = lane & 15;
    int lk = (lane >> 4) * 8;

    f32x4 acc[2][4] = {};
    for (int k0 = 0; k0 < 256; k0 += 32) {
        bf16x8 afrag[2], bfrag[4];
        #pragma unroll
        for (int i = 0; i < 2; ++i) {
            int row = bm + wm + i * 16 + lr;
            row = row < M ? row : M - 1;         // clamp; stores are guarded
            afrag[i] = cvt8(Q + (size_t)row * 256 + k0 + lk);
        }
        #pragma unroll
        for (int j = 0; j < 4; ++j) {
            int n = bn + wn + j * 16 + lr;
            const float* wp = (n < 256) ? (Woff + (size_t)n * 256)
                                        : (Wattn + (size_t)(n - 256) * 256);
            bfrag[j] = cvt8(wp + k0 + lk);
        }
        #pragma unroll
        for (int i = 0; i < 2; ++i)
            #pragma unroll
            for (int j = 0; j < 4; ++j)
                acc[i][j] = __builtin_amdgcn_mfma_f32_16x16x32_bf16(
                    afrag[i], bfrag[j], acc[i][j], 0, 0, 0);
    }

    #pragma unroll
    for (int i = 0; i < 2; ++i) {
        int mbase = bm + wm + i * 16 + (lane >> 4) * 4;
        #pragma unroll
        for (int j = 0; j < 4; ++j) {
            int n = bn + wn + j * 16 + (lane & 15);
            float bias = (n < 256) ? boff[n] : battn[n - 256];
            #pragma unroll
            for (int r = 0; r < 4; ++r) {
                int row = mbase + r;
                if (row < M) P[(size_t)row * 384 + n] = acc[i][j][r] + bias;
            }
        }
    }
}

// ---------------------------------------------------------------------------
// sampling, head-partitioned for XCD-L2 locality. block = (h, b, 8 queries),
// blockIdx%8 = h -> XCD h sees only head h's values (4x1.39MB ~ L2-sized).
// phase 1 (tid<128, tid=(q8,lp)): shuffle softmax (16 lanes) + corners,
//   attn folded; s_iw row (q8>>1)*388 + (8p+2l+(q8&1))*12 dwords ->
//   phase-2 b128 reads conflict-free, writes <=2-way.
// phase 2: tid = (l, q8, c4); per-p: 2 LDS int4 + 4 bf16x4 gathers + FMA;
//   LDS-reduce over l; float4 store per (q8,c4).
// ---------------------------------------------------------------------------
__global__ __launch_bounds__(256) void ms_deform_kernel(
    const float* __restrict__ rp,            // (BS, NQ, L, NK, 2)
    const float* __restrict__ proj,          // (BS*LEN_Q, 384)
    const unsigned short* __restrict__ vt,   // transposed bf16 values
    float* __restrict__ out)                 // (BS, LEN_Q, 256)
{
    int bid = blockIdx.x;
    int h   = bid & 7;            // XCD id under round-robin dispatch
    int b   = (bid >> 3) & 3;
    int qc  = bid >> 5;           // 0..637
    int q0  = qc * 8;

    __shared__ int s_iw[1552];
    __shared__ float4 s_red[256];

    int tid = threadIdx.x;

    if (tid < 128) {
        int q8 = tid >> 4;
        int lp = tid & 15;
        int l  = lp >> 2;
        int p  = lp & 3;
        int q  = q0 + q8;
        int qq = q < LEN_Q ? q : LEN_Q - 1;
        const float* prow = proj + (size_t)(b * LEN_Q + qq) * 384;

        // shuffle softmax over this head's 16 logits (lanes 16-aligned by q8)
        float g = prow[256 + h * 16 + lp];
        float mx = g;
        mx = fmaxf(mx, __shfl_xor(mx, 1, 16));
        mx = fmaxf(mx, __shfl_xor(mx, 2, 16));
        mx = fmaxf(mx, __shfl_xor(mx, 4, 16));
        mx = fmaxf(mx, __shfl_xor(mx, 8, 16));
        float e = __expf(g - mx);
        float s = e;
        s += __shfl_xor(s, 1, 16);
        s += __shfl_xor(s, 2, 16);
        s += __shfl_xor(s, 4, 16);
        s += __shfl_xor(s, 8, 16);
        float a = (q < LEN_Q) ? (e / s) : 0.f;

        int Wl = 128 >> l;            // square levels: 128,64,32,16
        float ww = (float)Wl;
        int qi = qq / NK;
        int ki = qq - qi * NK;
        size_t rbase = ((((size_t)b * NQ + qi) * N_LEVELS + l) * NK + ki) * 2;
        float rx = rp[rbase + 0];
        float ry = rp[rbase + 1];
        int oj = (h * 16 + lp) * 2;
        float ox = prow[oj], oy = prow[oj + 1];
        // grid_sample align_corners=False: x = loc*w - 0.5
        float x = (rx + ox / ww) * ww - 0.5f;
        float y = (ry + oy / ww) * ww - 0.5f;
        float x0f = floorf(x), y0f = floorf(y);
        float wx1 = x - x0f, wy1 = y - y0f;
        float wx0 = 1.f - wx1, wy0 = 1.f - wy1;
        int x0 = (int)x0f, y0 = (int)y0f;

        int* wrow = s_iw + (q8 >> 1) * 388 + (p * 8 + l * 2 + (q8 & 1)) * 12;
        #pragma unroll
        for (int corner = 0; corner < 4; ++corner) {
            int xi = x0 + (corner & 1);
            int yi = y0 + (corner >> 1);
            float wgt = ((corner & 1) ? wx1 : wx0) * ((corner >> 1) ? wy1 : wy0);
            bool valid = (xi >= 0) && (xi < Wl) && (yi >= 0) && (yi < Wl);
            int2 iw;
            iw.x = valid ? (yi * Wl + xi) * HD : 0;   // ushort-unit index
            iw.y = __float_as_int(valid ? wgt * a : 0.f);
            *(int2*)(wrow + corner * 2) = iw;
        }
    }
    __syncthreads();

    // phase 2: tid = l*64 + q8*8 + c4  (wave-uniform level)
    int l  = tid >> 6;
    int q8 = (tid >> 3) & 7;
    int c4 = tid & 7;
    int n  = b * N_HEADS + h;
    const size_t lb[4]  = {LB0, LB1, LB2, LB3};
    const int    Ssz[4] = {16384, 4096, 1024, 256};

    const unsigned short* vbase = vt + lb[l] + (size_t)n * Ssz[l] * HD + c4 * 4;
    const int* rrow0 = s_iw + (q8 >> 1) * 388 + (l * 2 + (q8 & 1)) * 12;

    float4 acc = make_float4(0.f, 0.f, 0.f, 0.f);
    #pragma unroll
    for (int p = 0; p < 4; ++p) {
        const int* rr = rrow0 + p * 96;                 // p*8 rows * 12 dwords
        int4 A  = *(const int4*)rr;                     // corners 0,1
        int4 Bv = *(const int4*)(rr + 4);               // corners 2,3
        ushort4 u0 = *(const ushort4*)(vbase + A.x);
        ushort4 u1 = *(const ushort4*)(vbase + A.z);
        ushort4 u2 = *(const ushort4*)(vbase + Bv.x);
        ushort4 u3 = *(const ushort4*)(vbase + Bv.z);
        float w0 = __int_as_float(A.y);
        float w1 = __int_as_float(A.w);
        float w2 = __int_as_float(Bv.y);
        float w3 = __int_as_float(Bv.w);
        acc.x += w0 * bf2f(u0.x) + w1 * bf2f(u1.x) + w2 * bf2f(u2.x) + w3 * bf2f(u3.x);
        acc.y += w0 * bf2f(u0.y) + w1 * bf2f(u1.y) + w2 * bf2f(u2.y) + w3 * bf2f(u3.y);
        acc.z += w0 * bf2f(u0.z) + w1 * bf2f(u1.z) + w2 * bf2f(u2.z) + w3 * bf2f(u3.z);
        acc.w += w0 * bf2f(u0.w) + w1 * bf2f(u1.w) + w2 * bf2f(u2.w) + w3 * bf2f(u3.w);
    }

    s_red[tid] = acc;
    __syncthreads();
    if (tid < 64) {
        int q8o = tid >> 3;
        int c4o = tid & 7;
        int base = q8o * 8 + c4o;
        float4 a0 = s_red[base];
        float4 a1 = s_red[base + 64];
        float4 a2 = s_red[base + 128];
        float4 a3 = s_red[base + 192];
        float4 o;
        o.x = a0.x + a1.x + a2.x + a3.x;
        o.y = a0.y + a1.y + a2.y + a3.y;
        o.z = a0.z + a1.z + a2.z + a3.z;
        o.w = a0.w + a1.w + a2.w + a3.w;
        int q = q0 + q8o;
        if (q < LEN_Q)
            *(float4*)(out + (size_t)(b * LEN_Q + q) * 256 + h * 32 + c4o * 4) = o;
    }
}

// ---------------------------------------------------------------------------
extern "C" void kernel_launch(void* const* d_in, const int* in_sizes, int n_in,
                              void* d_out, int out_size, void* d_ws, size_t ws_size,
                              hipStream_t stream)
{
    const float* query = (const float*)d_in[0];
    const float* refp  = (const float*)d_in[1];
    const float* v0    = (const float*)d_in[2];
    const float* v1    = (const float*)d_in[3];
    const float* v2    = (const float*)d_in[4];
    const float* v3    = (const float*)d_in[5];
    const float* Woff  = (const float*)d_in[6];
    const float* boff  = (const float*)d_in[7];
    const float* Wattn = (const float*)d_in[8];
    const float* battn = (const float*)d_in[9];
    float* out = (float*)d_out;
    unsigned short* vt = (unsigned short*)d_ws;
    float* proj = (float*)(vt + VT_TOTAL);    // 44.6 MB offset, 4B-aligned

    // 1) fused transpose all levels -> bf16 (n, s, c)
    transpose_bf16_kernel<<<dim3(680, 32), dim3(32, 8), 0, stream>>>(
        v0, v1, v2, v3, vt);

    // 2) fused projection MFMA GEMM -> (M, 384) = [off(256) | attn_logits(128)]
    int M = BS * LEN_Q;                       // 20400
    proj_gemm_mfma<<<dim3(3, (M + 63) / 64), 256, 0, stream>>>(
        query, Woff, boff, Wattn, battn, proj, M);

    // 3) sampling: (638 q-chunks) x (4 b) x (8 h); blockIdx%8 = h -> XCD h
    ms_deform_kernel<<<638 * 32, 256, 0, stream>>>(refp, proj, vt, out);
}